// Round 1
// baseline (84.994 us; speedup 1.0000x reference)
//
#include <hip/hip_runtime.h>
#include <math.h>

// SpheresRasterizer: B=1, N=1024 points, H=W=256, K=8 points per pixel.
// Outputs (idx, zbuf, dists) each B*H*W*K, concatenated flat; all written as
// float32 (idx values are exact small integers, representable in f32).
//
// Strategy: one block per image row (256 threads = 256 pixels). Each block
// cooperatively transforms all N points (world -> view -> screen) into LDS
// as float4 {x_screen, y_screen, z_view, r2_eff}, where r2_eff = r*r if
// z_view > 0 else -1 (folds the z>0 test into the dist2 <= r2 test).
// Then each thread keeps a sorted 8-deep (z, idx, dist2) insertion list in
// registers (compile-time indices only).

#define KPP 8

__global__ __launch_bounds__(256) void sphere_raster_kernel(
    const float* __restrict__ points,   // B*N*3
    const float* __restrict__ radius,   // B*N
    const float* __restrict__ w2v,      // B*16, row-major [k][l]
    const float* __restrict__ proj,     // B*16
    float* __restrict__ out,            // 3 * B*H*W*KPP floats
    int B, int N, int H, int W)
{
    extern __shared__ float4 sh[];      // N entries

    const int j = threadIdx.x;          // column
    const int i = blockIdx.x % H;       // row
    const int b = blockIdx.x / H;

    const float* M1 = w2v + (size_t)b * 16;
    const float* M2 = proj + (size_t)b * 16;

    // ---- Phase 1: transform all points (block-cooperative) ----
    for (int t = threadIdx.x; t < N; t += blockDim.x) {
        const float* p = points + ((size_t)b * N + t) * 3;
        float x = p[0], y = p[1], z = p[2];
        // [x,y,z,1] @ M1  (sum over k: ph[k]*M[k][l])
        float vx = ((x * M1[0] + y * M1[4]) + z * M1[8])  + M1[12];
        float vy = ((x * M1[1] + y * M1[5]) + z * M1[9])  + M1[13];
        float vz = ((x * M1[2] + y * M1[6]) + z * M1[10]) + M1[14];
        float vw = ((x * M1[3] + y * M1[7]) + z * M1[11]) + M1[15];
        float w1 = (fabsf(vw) < 1e-8f) ? 1e-8f : vw;
        vx /= w1; vy /= w1; vz /= w1;
        // view -> screen
        float sx = ((vx * M2[0] + vy * M2[4]) + vz * M2[8])  + M2[12];
        float sy = ((vx * M2[1] + vy * M2[5]) + vz * M2[9])  + M2[13];
        float sw = ((vx * M2[3] + vy * M2[7]) + vz * M2[11]) + M2[15];
        float w2 = (fabsf(sw) < 1e-8f) ? 1e-8f : sw;
        sx /= w2; sy /= w2;
        // z in screen space is replaced by view-space z (reference does .at[...,2].set)
        float r  = radius[(size_t)b * N + t];
        float r2 = r * r;
        float r2eff = (vz > 0.0f) ? r2 : -1.0f;   // dist2 >= 0, so dist2 <= -1 is never true
        sh[t] = make_float4(sx, sy, vz, r2eff);
    }
    __syncthreads();

    // ---- Phase 2: rasterize one pixel per thread ----
    // coords = linspace(half, -half, W) with half = 1 - 1/W (computed in f64, cast f32)
    const double halfd = 1.0 - 1.0 / (double)W;
    const float px = (float)(halfd - (double)j * (2.0 * halfd / (double)(W - 1)));
    const float py = (float)(halfd - (double)i * (2.0 * halfd / (double)(H - 1)));

    float zb[KPP];
    int   id[KPP];
    float dd[KPP];
#pragma unroll
    for (int k = 0; k < KPP; ++k) { zb[k] = INFINITY; id[k] = -1; dd[k] = -1.0f; }

#pragma unroll 4
    for (int n = 0; n < N; ++n) {
        float4 p = sh[n];
        float dx = p.x - px;
        float dy = p.y - py;
        // match numpy exactly: dx*dx + dy*dy, no FMA contraction
        float dist2 = __fadd_rn(__fmul_rn(dx, dx), __fmul_rn(dy, dy));
        bool inside = (dist2 <= p.w);     // p.w = r2eff already encodes z>0
        if (inside && (p.z < zb[KPP - 1])) {
            float zc = p.z; int ic = n; float dc = dist2;
#pragma unroll
            for (int k = 0; k < KPP; ++k) {
                bool lt = (zc < zb[k]);   // strict: preserves ascending-index tie order
                float tz = zb[k]; int ti = id[k]; float td = dd[k];
                if (lt) { zb[k] = zc; id[k] = ic; dd[k] = dc; zc = tz; ic = ti; dc = td; }
            }
        }
    }

    // ---- Phase 3: write outputs ----
    const size_t pix   = ((size_t)b * H + i) * W + j;
    const size_t plane = (size_t)B * H * W * KPP;
    float* oidx = out;
    float* ozbf = out + plane;
    float* odst = out + 2 * plane;
#pragma unroll
    for (int k = 0; k < KPP; ++k) {
        bool valid = (zb[k] != INFINITY);
        oidx[pix * KPP + k] = valid ? (float)id[k] : -1.0f;
        ozbf[pix * KPP + k] = valid ? zb[k]        : -1.0f;
        odst[pix * KPP + k] = valid ? dd[k]        : -1.0f;
    }
}

extern "C" void kernel_launch(void* const* d_in, const int* in_sizes, int n_in,
                              void* d_out, int out_size, void* d_ws, size_t ws_size,
                              hipStream_t stream) {
    const float* points = (const float*)d_in[0];
    const float* radius = (const float*)d_in[1];
    const float* w2v    = (const float*)d_in[2];
    const float* proj   = (const float*)d_in[3];
    // image_size / points_per_pixel live in device memory (1-elem arrays); derive
    // geometry from host-visible sizes instead: K is fixed at 8 (setup_inputs).
    int B = in_sizes[2] / 16;
    if (B < 1) B = 1;
    int N = in_sizes[1] / B;
    int HW = out_size / (3 * B * KPP);      // H*W
    int H = 1;
    while ((H + 1) * (H + 1) <= HW) ++H;    // integer sqrt
    int W = H;

    dim3 grid(B * H);
    dim3 block(W);
    size_t shmem = (size_t)N * sizeof(float4);
    sphere_raster_kernel<<<grid, block, shmem, stream>>>(
        points, radius, w2v, proj, (float*)d_out, B, N, H, W);
}

// Round 2
// 21.198 us; speedup vs baseline: 4.0095x; 4.0095x over previous
//
#include <hip/hip_runtime.h>
#include <math.h>

// SpheresRasterizer: B=1, N=1024 points, H=W=256, K=8.
// Round 2: row-band culling + stream compaction + 8-wide batched LDS reads.
//
// One block per image row (256 threads = 256 pixels, 4 waves). Each thread
// transforms 4 contiguous points, keeps those whose screen-y band overlaps
// this row (dy*dy <= r2eff, exact-conservative since dist2 >= dy^2 in f32),
// and compacts survivors (order-preserving: wave-prefix via shfl_up, block
// prefix via LDS) into an LDS list. Each pixel then scans only the compacted
// list in batches of 8 (independent ds_read_b128s -> one latency per batch).

#define KPP 8

__global__ __launch_bounds__(256) void sphere_raster_kernel(
    const float* __restrict__ points,   // B*N*3
    const float* __restrict__ radius,   // B*N
    const float* __restrict__ w2v,      // B*16
    const float* __restrict__ proj,     // B*16
    float* __restrict__ out,            // 3 * B*H*W*KPP floats
    int B, int N, int H, int W)
{
    extern __shared__ char smem[];
    float4* cmp  = (float4*)smem;                              // N entries
    int*    cidx = (int*)(smem + (size_t)N * sizeof(float4));  // N entries
    __shared__ int wsum[4];

    const int j    = threadIdx.x;          // column
    const int i    = blockIdx.x % H;       // row
    const int b    = blockIdx.x / H;
    const int lane = threadIdx.x & 63;
    const int wid  = threadIdx.x >> 6;

    const float* M1 = w2v  + (size_t)b * 16;
    const float* M2 = proj + (size_t)b * 16;

    // linspace(half,-half,W): f64 math, cast f32 (matched round-1 numerics)
    const double halfd = 1.0 - 1.0 / (double)W;
    const float px = (float)(halfd - (double)j * (2.0 * halfd / (double)(W - 1)));
    const float py = (float)(halfd - (double)i * (2.0 * halfd / (double)(H - 1)));

    // ---- Phase 1: transform 4 contiguous points/thread, cull to row band ----
    const int t0 = threadIdx.x * 4;        // global point base (N == 4*blockDim)
    float4 P[4];
    int keep[4];
    int c = 0;

    // 4 points = 12 floats = 3 aligned float4 loads; radius = 1 float4
    const float4* pv = (const float4*)(points + ((size_t)b * N + t0) * 3);
    float4 q0 = pv[0], q1 = pv[1], q2 = pv[2];
    float4 rr = *(const float4*)(radius + (size_t)b * N + t0);
    float xs[4] = {q0.x, q0.w, q1.z, q2.y};
    float ys[4] = {q0.y, q1.x, q1.w, q2.z};
    float zs[4] = {q0.z, q1.y, q2.x, q2.w};
    float rv[4] = {rr.x, rr.y, rr.z, rr.w};

#pragma unroll
    for (int s = 0; s < 4; ++s) {
        float x = xs[s], y = ys[s], z = zs[s];
        float vx = ((x * M1[0] + y * M1[4]) + z * M1[8])  + M1[12];
        float vy = ((x * M1[1] + y * M1[5]) + z * M1[9])  + M1[13];
        float vz = ((x * M1[2] + y * M1[6]) + z * M1[10]) + M1[14];
        float vw = ((x * M1[3] + y * M1[7]) + z * M1[11]) + M1[15];
        float w1 = (fabsf(vw) < 1e-8f) ? 1e-8f : vw;
        vx /= w1; vy /= w1; vz /= w1;
        float sx = ((vx * M2[0] + vy * M2[4]) + vz * M2[8])  + M2[12];
        float sy = ((vx * M2[1] + vy * M2[5]) + vz * M2[9])  + M2[13];
        float sw = ((vx * M2[3] + vy * M2[7]) + vz * M2[11]) + M2[15];
        float w2 = (fabsf(sw) < 1e-8f) ? 1e-8f : sw;
        sx /= w2; sy /= w2;
        float r = rv[s];
        float r2eff = (vz > 0.0f) ? r * r : -1.0f;
        float dy = sy - py;
        keep[s] = (__fmul_rn(dy, dy) <= r2eff) ? 1 : 0;  // exact-conservative
        P[s] = make_float4(sx, sy, vz, r2eff);
        c += keep[s];
    }

    // ---- order-preserving compaction: wave inclusive scan + block offsets ----
    int pre = c;
#pragma unroll
    for (int d = 1; d < 64; d <<= 1) {
        int v = __shfl_up(pre, d);
        if (lane >= d) pre += v;
    }
    if (lane == 63) wsum[wid] = pre;
    __syncthreads();
    int wbase = 0, M = 0;
#pragma unroll
    for (int w = 0; w < 4; ++w) {
        int ws = wsum[w];
        if (w < wid) wbase += ws;
        M += ws;
    }
    int pos = wbase + (pre - c);           // exclusive prefix of this thread
#pragma unroll
    for (int s = 0; s < 4; ++s) {
        if (keep[s]) { cmp[pos] = P[s]; cidx[pos] = t0 + s; ++pos; }
    }
    __syncthreads();

    // ---- Phase 2: scan compacted list, 8-wide batched loads ----
    float zb[KPP]; int id[KPP]; float dd[KPP];
#pragma unroll
    for (int k = 0; k < KPP; ++k) { zb[k] = INFINITY; id[k] = -1; dd[k] = -1.0f; }

    int n = 0;
    for (; n + 8 <= M; n += 8) {
        float4 pp[8];
#pragma unroll
        for (int u = 0; u < 8; ++u) pp[u] = cmp[n + u];
        int4 ia = *(const int4*)&cidx[n];
        int4 ib = *(const int4*)&cidx[n + 4];
        int ii[8] = {ia.x, ia.y, ia.z, ia.w, ib.x, ib.y, ib.z, ib.w};
#pragma unroll
        for (int u = 0; u < 8; ++u) {
            float dx = pp[u].x - px;
            float dy = pp[u].y - py;
            float dist2 = __fadd_rn(__fmul_rn(dx, dx), __fmul_rn(dy, dy));
            if ((dist2 <= pp[u].w) && (pp[u].z < zb[KPP - 1])) {
                float zc = pp[u].z; int ic = ii[u]; float dc = dist2;
#pragma unroll
                for (int k = 0; k < KPP; ++k) {
                    bool lt = (zc < zb[k]);
                    float tz = zb[k]; int ti = id[k]; float td = dd[k];
                    if (lt) { zb[k] = zc; id[k] = ic; dd[k] = dc; zc = tz; ic = ti; dc = td; }
                }
            }
        }
    }
    for (; n < M; ++n) {
        float4 p = cmp[n];
        int ic0 = cidx[n];
        float dx = p.x - px;
        float dy = p.y - py;
        float dist2 = __fadd_rn(__fmul_rn(dx, dx), __fmul_rn(dy, dy));
        if ((dist2 <= p.w) && (p.z < zb[KPP - 1])) {
            float zc = p.z; int ic = ic0; float dc = dist2;
#pragma unroll
            for (int k = 0; k < KPP; ++k) {
                bool lt = (zc < zb[k]);
                float tz = zb[k]; int ti = id[k]; float td = dd[k];
                if (lt) { zb[k] = zc; id[k] = ic; dd[k] = dc; zc = tz; ic = ti; dc = td; }
            }
        }
    }

    // ---- Phase 3: write outputs (2 float4 stores per plane) ----
    const size_t pix   = ((size_t)b * H + i) * W + j;
    const size_t plane = (size_t)B * H * W * KPP;
    float vidx[KPP], vzbf[KPP], vdst[KPP];
#pragma unroll
    for (int k = 0; k < KPP; ++k) {
        bool valid = (zb[k] != INFINITY);
        vidx[k] = valid ? (float)id[k] : -1.0f;
        vzbf[k] = valid ? zb[k]        : -1.0f;
        vdst[k] = valid ? dd[k]        : -1.0f;
    }
    float* oidx = out + pix * KPP;
    float* ozbf = out + plane + pix * KPP;
    float* odst = out + 2 * plane + pix * KPP;
    *(float4*)(oidx)     = make_float4(vidx[0], vidx[1], vidx[2], vidx[3]);
    *(float4*)(oidx + 4) = make_float4(vidx[4], vidx[5], vidx[6], vidx[7]);
    *(float4*)(ozbf)     = make_float4(vzbf[0], vzbf[1], vzbf[2], vzbf[3]);
    *(float4*)(ozbf + 4) = make_float4(vzbf[4], vzbf[5], vzbf[6], vzbf[7]);
    *(float4*)(odst)     = make_float4(vdst[0], vdst[1], vdst[2], vdst[3]);
    *(float4*)(odst + 4) = make_float4(vdst[4], vdst[5], vdst[6], vdst[7]);
}

extern "C" void kernel_launch(void* const* d_in, const int* in_sizes, int n_in,
                              void* d_out, int out_size, void* d_ws, size_t ws_size,
                              hipStream_t stream) {
    const float* points = (const float*)d_in[0];
    const float* radius = (const float*)d_in[1];
    const float* w2v    = (const float*)d_in[2];
    const float* proj   = (const float*)d_in[3];
    int B = in_sizes[2] / 16;
    if (B < 1) B = 1;
    int N = in_sizes[1] / B;                 // radius has N elements
    int HW = out_size / (3 * B * KPP);
    int H = 1;
    while ((H + 1) * (H + 1) <= HW) ++H;     // integer sqrt
    int W = H;

    dim3 grid(B * H);
    dim3 block(W);                           // 256 threads, 4 waves
    size_t shmem = (size_t)N * (sizeof(float4) + sizeof(int));
    sphere_raster_kernel<<<grid, block, shmem, stream>>>(
        points, radius, w2v, proj, (float*)d_out, B, N, H, W);
}

// Round 3
// 14.704 us; speedup vs baseline: 5.7802x; 1.4416x over previous
//
#include <hip/hip_runtime.h>
#include <math.h>

// SpheresRasterizer: B=1, N=1024 points, H=W=256, K=8.
// Round 3: 16x16 pixel TILE blocks with 2-D conservative box culling.
//
// One block per 16x16 tile (256 threads, 1 pixel each). Each thread
// transforms 4 contiguous points, keeps those whose sphere can touch the
// tile's pixel box (min box-distance^2 <= r2, box inflated by one pixel
// + 1e-6 so the exact per-pixel f32 test is always a subset), compacts
// survivors order-preservingly into LDS, then each pixel scans the short
// list in batches of 8 with the exact reference arithmetic.

#define KPP 8

__global__ __launch_bounds__(256) void sphere_raster_kernel(
    const float* __restrict__ points,   // B*N*3
    const float* __restrict__ radius,   // B*N
    const float* __restrict__ w2v,      // B*16
    const float* __restrict__ proj,     // B*16
    float* __restrict__ out,            // 3 * B*H*W*KPP floats
    int B, int N, int H, int W)
{
    extern __shared__ char smem[];
    float4* cmp  = (float4*)smem;                              // N entries
    int*    cidx = (int*)(smem + (size_t)N * sizeof(float4));  // N entries
    __shared__ int wsum[4];

    const int TS = 16;                      // tile side
    const int tilesX = W / TS;
    const int tile   = blockIdx.x % (tilesX * (H / TS));
    const int b      = blockIdx.x / (tilesX * (H / TS));
    const int tx0    = (tile % tilesX) * TS;
    const int ty0    = (tile / tilesX) * TS;
    const int j      = tx0 + (threadIdx.x & (TS - 1));   // column
    const int i      = ty0 + (threadIdx.x >> 4);         // row
    const int lane   = threadIdx.x & 63;
    const int wid    = threadIdx.x >> 6;

    const float* M1 = w2v  + (size_t)b * 16;
    const float* M2 = proj + (size_t)b * 16;

    // linspace(half,-half,W): f64 math, cast f32 (matches reference numerics)
    const double halfd = 1.0 - 1.0 / (double)W;
    const double step  = 2.0 * halfd / (double)(W - 1);
    const float px = (float)(halfd - (double)j * step);
    const float py = (float)(halfd - (double)i * step);

    // tile pixel-box center/half-extent in NDC (coords descend with index)
    const float cx = (float)(halfd - ((double)tx0 + (TS - 1) * 0.5) * step);
    const float cy = (float)(halfd - ((double)ty0 + (TS - 1) * 0.5) * step);
    const float hext = (float)(((TS - 1) * 0.5 + 1.0) * step);  // +1px inflation

    // ---- Phase 1: transform 4 contiguous points/thread, cull to tile box ----
    const int t0 = threadIdx.x * 4;         // N == 4*blockDim
    float4 P[4];
    int keep[4];
    int c = 0;

    const float4* pv = (const float4*)(points + ((size_t)b * N + t0) * 3);
    float4 q0 = pv[0], q1 = pv[1], q2 = pv[2];
    float4 rr = *(const float4*)(radius + (size_t)b * N + t0);
    float xs[4] = {q0.x, q0.w, q1.z, q2.y};
    float ys[4] = {q0.y, q1.x, q1.w, q2.z};
    float zs[4] = {q0.z, q1.y, q2.x, q2.w};
    float rv[4] = {rr.x, rr.y, rr.z, rr.w};

#pragma unroll
    for (int s = 0; s < 4; ++s) {
        float x = xs[s], y = ys[s], z = zs[s];
        float vx = ((x * M1[0] + y * M1[4]) + z * M1[8])  + M1[12];
        float vy = ((x * M1[1] + y * M1[5]) + z * M1[9])  + M1[13];
        float vz = ((x * M1[2] + y * M1[6]) + z * M1[10]) + M1[14];
        float vw = ((x * M1[3] + y * M1[7]) + z * M1[11]) + M1[15];
        float w1 = (fabsf(vw) < 1e-8f) ? 1e-8f : vw;
        vx /= w1; vy /= w1; vz /= w1;
        float sx = ((vx * M2[0] + vy * M2[4]) + vz * M2[8])  + M2[12];
        float sy = ((vx * M2[1] + vy * M2[5]) + vz * M2[9])  + M2[13];
        float sw = ((vx * M2[3] + vy * M2[7]) + vz * M2[11]) + M2[15];
        float w2 = (fabsf(sw) < 1e-8f) ? 1e-8f : sw;
        sx /= w2; sy /= w2;
        float r = rv[s];
        float r2eff = (vz > 0.0f) ? r * r : -1.0f;
        // conservative min distance^2 from sphere center to tile pixel box
        float dxm = fmaxf(0.0f, fabsf(sx - cx) - hext);
        float dym = fmaxf(0.0f, fabsf(sy - cy) - hext);
        float dmin2 = dxm * dxm + dym * dym;
        keep[s] = (dmin2 <= r2eff + 1e-6f) ? 1 : 0;
        P[s] = make_float4(sx, sy, vz, r2eff);
        c += keep[s];
    }

    // ---- order-preserving compaction ----
    int pre = c;
#pragma unroll
    for (int d = 1; d < 64; d <<= 1) {
        int v = __shfl_up(pre, d);
        if (lane >= d) pre += v;
    }
    if (lane == 63) wsum[wid] = pre;
    __syncthreads();
    int wbase = 0, M = 0;
#pragma unroll
    for (int w = 0; w < 4; ++w) {
        int ws = wsum[w];
        if (w < wid) wbase += ws;
        M += ws;
    }
    int pos = wbase + (pre - c);
#pragma unroll
    for (int s = 0; s < 4; ++s) {
        if (keep[s]) { cmp[pos] = P[s]; cidx[pos] = t0 + s; ++pos; }
    }
    __syncthreads();

    // ---- Phase 2: scan compacted list, 8-wide batched broadcast loads ----
    float zb[KPP]; int id[KPP]; float dd[KPP];
#pragma unroll
    for (int k = 0; k < KPP; ++k) { zb[k] = INFINITY; id[k] = -1; dd[k] = -1.0f; }

    int n = 0;
    for (; n + 8 <= M; n += 8) {
        float4 pp[8];
#pragma unroll
        for (int u = 0; u < 8; ++u) pp[u] = cmp[n + u];
        int4 ia = *(const int4*)&cidx[n];
        int4 ib = *(const int4*)&cidx[n + 4];
        int ii[8] = {ia.x, ia.y, ia.z, ia.w, ib.x, ib.y, ib.z, ib.w};
#pragma unroll
        for (int u = 0; u < 8; ++u) {
            float dx = pp[u].x - px;
            float dy = pp[u].y - py;
            float dist2 = __fadd_rn(__fmul_rn(dx, dx), __fmul_rn(dy, dy));
            if ((dist2 <= pp[u].w) && (pp[u].z < zb[KPP - 1])) {
                float zc = pp[u].z; int ic = ii[u]; float dc = dist2;
#pragma unroll
                for (int k = 0; k < KPP; ++k) {
                    bool lt = (zc < zb[k]);
                    float tz = zb[k]; int ti = id[k]; float td = dd[k];
                    if (lt) { zb[k] = zc; id[k] = ic; dd[k] = dc; zc = tz; ic = ti; dc = td; }
                }
            }
        }
    }
    for (; n < M; ++n) {
        float4 p = cmp[n];
        int ic0 = cidx[n];
        float dx = p.x - px;
        float dy = p.y - py;
        float dist2 = __fadd_rn(__fmul_rn(dx, dx), __fmul_rn(dy, dy));
        if ((dist2 <= p.w) && (p.z < zb[KPP - 1])) {
            float zc = p.z; int ic = ic0; float dc = dist2;
#pragma unroll
            for (int k = 0; k < KPP; ++k) {
                bool lt = (zc < zb[k]);
                float tz = zb[k]; int ti = id[k]; float td = dd[k];
                if (lt) { zb[k] = zc; id[k] = ic; dd[k] = dc; zc = tz; ic = ti; dc = td; }
            }
        }
    }

    // ---- Phase 3: write outputs (2 float4 stores per plane) ----
    const size_t pix   = ((size_t)b * H + i) * W + j;
    const size_t plane = (size_t)B * H * W * KPP;
    float vidx[KPP], vzbf[KPP], vdst[KPP];
#pragma unroll
    for (int k = 0; k < KPP; ++k) {
        bool valid = (zb[k] != INFINITY);
        vidx[k] = valid ? (float)id[k] : -1.0f;
        vzbf[k] = valid ? zb[k]        : -1.0f;
        vdst[k] = valid ? dd[k]        : -1.0f;
    }
    float* oidx = out + pix * KPP;
    float* ozbf = out + plane + pix * KPP;
    float* odst = out + 2 * plane + pix * KPP;
    *(float4*)(oidx)     = make_float4(vidx[0], vidx[1], vidx[2], vidx[3]);
    *(float4*)(oidx + 4) = make_float4(vidx[4], vidx[5], vidx[6], vidx[7]);
    *(float4*)(ozbf)     = make_float4(vzbf[0], vzbf[1], vzbf[2], vzbf[3]);
    *(float4*)(ozbf + 4) = make_float4(vzbf[4], vzbf[5], vzbf[6], vzbf[7]);
    *(float4*)(odst)     = make_float4(vdst[0], vdst[1], vdst[2], vdst[3]);
    *(float4*)(odst + 4) = make_float4(vdst[4], vdst[5], vdst[6], vdst[7]);
}

extern "C" void kernel_launch(void* const* d_in, const int* in_sizes, int n_in,
                              void* d_out, int out_size, void* d_ws, size_t ws_size,
                              hipStream_t stream) {
    const float* points = (const float*)d_in[0];
    const float* radius = (const float*)d_in[1];
    const float* w2v    = (const float*)d_in[2];
    const float* proj   = (const float*)d_in[3];
    int B = in_sizes[2] / 16;
    if (B < 1) B = 1;
    int N = in_sizes[1] / B;
    int HW = out_size / (3 * B * KPP);
    int H = 1;
    while ((H + 1) * (H + 1) <= HW) ++H;     // integer sqrt
    int W = H;

    int tiles = (W / 16) * (H / 16);
    dim3 grid(B * tiles);
    dim3 block(256);
    size_t shmem = (size_t)N * (sizeof(float4) + sizeof(int));
    sphere_raster_kernel<<<grid, block, shmem, stream>>>(
        points, radius, w2v, proj, (float*)d_out, B, N, H, W);
}